// Round 9
// baseline (389.436 us; speedup 1.0000x reference)
//
#include <hip/hip_runtime.h>
#include <math.h>

// Problem constants (fixed by reference)
#define B_TOT   256
#define N_TOT   2304
#define IN_DIM  8
#define NC      10      // NUM_CLASSES
#define OD      16      // OUT_DIM
#define CD      160     // NC*OD
#define RBIAS   0.1f

#define NS      128                     // n-slices (part slabs)
#define NPB     (N_TOT / NS)            // 18 n per slab
#define WROW    (IN_DIM * CD)           // 1280 floats per W row
#define NF4     (B_TOT * CD / 4)        // 10240 float4 per partial slab
#define NXCD    8

typedef __attribute__((ext_vector_type(8))) short bf16x8;
typedef __attribute__((ext_vector_type(4))) float f32x4;

// RNE round fp32 -> bf16, result kept top-aligned in a dword
__device__ __forceinline__ unsigned int rne_hi(unsigned int b) {
    return (b + 0x7FFFu + ((b >> 16) & 1u)) & 0xFFFF0000u;
}
// exact-ish 2-way split: f = hi + lo + O(2^-17 |f|); hi RNE, lo truncated
__device__ __forceinline__ void split2(float f, unsigned int& h, unsigned int& l) {
    unsigned int xb = __float_as_uint(f);
    h = rne_hi(xb);
    float fl = f - __uint_as_float(h);
    l = __float_as_uint(fl) & 0xFFFF0000u;
}

// ===== Routing round, R9: MFMA formulation. u = x.W per n is a
// [16b x 8i]x[8i x 16d] GEMM per class -> mfma_f32_16x16x32_bf16 with
// 2-way bf16 splits filling K=32 as (xh,xh,xl,xl)*(wh,wl,wh,wl) per i
// (all 4 cross terms -> fp32-grade accuracy). W/x are loaded LANE-DISTINCT
// and coalesced (the MFMA crossbar does the broadcast the scalar-K$ /
// LDS-broadcast / readlane paths all paid 50-80us for, R1-R8 ledger).
// Each wave owns 16 b-rows x all 10 classes x 18 n: softmax is fully
// in-wave (4 shfl_xor per logit) -> NO LDS, NO barriers at all.
// Layout (verified m89/m91 C-map, m156/m162 k-map): row/col = lane&15,
// k = 4*(lane>>4)+j (j<4), 16+4*(lane>>4)+(j-4) (j>=4); C row = 4*(lane>>4)+reg.
template <int FIRST>
__global__ __launch_bounds__(512) void routing_round(
    const float* __restrict__ x,      // [B, N, 8]
    const float* __restrict__ W,      // [N, 8, 160]
    const float* __restrict__ S_acc,  // [B, 160]
    float* __restrict__ part)         // [NS, B, 160]
{
    const int tid  = threadIdx.x;
    const int lane = tid & 63;
    const int w    = tid >> 6;          // 0..7
    const int col  = lane & 15;         // d-col / A b-row selector
    const int g    = lane >> 4;         // 0..3: k-group -> i = g, g+4

    // XCD swizzle (confirmed R1): both b-halves of a slab on one XCD.
    const int bid   = blockIdx.x;       // 0..255 = 1 block/CU
    const int xcd   = bid & (NXCD - 1);
    const int slot  = bid >> 3;         // 0..31
    const int y     = xcd * 16 + (slot & 15);   // 0..127
    const int bhalf = slot >> 4;
    const int b0    = bhalf * 128 + w * 16;
    const int n0    = y * NPB;

    const int brow = b0 + 4 * g;        // C rows: brow + reg

    // ---- S fragments in C layout (once; n-independent)
    f32x4 S[NC];
    if (!FIRST) {
        #pragma unroll
        for (int c = 0; c < NC; c++)
            #pragma unroll
            for (int r = 0; r < 4; r++)
                S[c][r] = S_acc[(size_t)(brow + r) * CD + c * OD + col];
    }

    f32x4 acc[NC];
    #pragma unroll
    for (int c = 0; c < NC; c++) acc[c] = (f32x4){0.f, 0.f, 0.f, 0.f};

    const float* xp = x + ((size_t)(b0 + col) * N_TOT + n0) * IN_DIM + g;
    const float* wp = W + (size_t)n0 * WROW + g * CD + col;

    for (int nn = 0; nn < NPB; nn++) {
        // ---- A frag: x[b0+col, n, i=g and g+4], split to bf16 pairs
        const float f0 = xp[0];
        const float f1 = xp[4];
        unsigned int h0, l0, h1, l1;
        split2(f0, h0, l0);
        split2(f1, h1, l1);
        union { unsigned int d[4]; bf16x8 v; } A;
        A.d[0] = (h0 >> 16) | h0;   // k 4g..4g+1  : xh,xh
        A.d[1] = (l0 >> 16) | l0;   // k 4g+2,4g+3 : xl,xl
        A.d[2] = (h1 >> 16) | h1;   // k 16+4g..   : xh',xh'
        A.d[3] = (l1 >> 16) | l1;   //              xl',xl'

        // ---- 10 classes: coalesced lane-distinct W loads -> B frag -> MFMA
        f32x4 u[NC];
        #pragma unroll
        for (int c = 0; c < NC; c++) {
            const float wlo = wp[c * OD];          // W[n, g,   c*16+col]
            const float whi = wp[640 + c * OD];    // W[n, g+4, c*16+col]
            unsigned int wh0, wl0, wh1, wl1;
            split2(wlo, wh0, wl0);
            split2(whi, wh1, wl1);
            union { unsigned int d[4]; bf16x8 v; } Bf;
            const unsigned int p0 = (wh0 >> 16) | wl0;   // wh,wl
            const unsigned int p1 = (wh1 >> 16) | wl1;
            Bf.d[0] = p0; Bf.d[1] = p0;                  // k 4g..4g+3
            Bf.d[2] = p1; Bf.d[3] = p1;                  // k 16+4g..
            u[c] = __builtin_amdgcn_mfma_f32_16x16x32_bf16(
                       A.v, Bf.v, (f32x4){0.f, 0.f, 0.f, 0.f}, 0, 0, 0);
        }

        if (!FIRST) {
            // in-wave softmax per owned b-row (reg): logits via 16-lane reduce
            #pragma unroll
            for (int r = 0; r < 4; r++) {
                float lg[NC];
                #pragma unroll
                for (int c = 0; c < NC; c++) {
                    float p = u[c][r] * S[c][r];
                    p += __shfl_xor(p, 1, 64);
                    p += __shfl_xor(p, 2, 64);
                    p += __shfl_xor(p, 4, 64);
                    p += __shfl_xor(p, 8, 64);
                    lg[c] = p;
                }
                float m = lg[0];
                #pragma unroll
                for (int c = 1; c < NC; c++) m = fmaxf(m, lg[c]);
                float den = 0.f;
                float e[NC];
                #pragma unroll
                for (int c = 0; c < NC; c++) { e[c] = __expf(lg[c] - m); den += e[c]; }
                const float rden = 1.f / den;
                #pragma unroll
                for (int c = 0; c < NC; c++)
                    acc[c][r] = fmaf(e[c] * rden, u[c][r], acc[c][r]);
            }
        } else {
            #pragma unroll
            for (int c = 0; c < NC; c++)
                #pragma unroll
                for (int r = 0; r < 4; r++) acc[c][r] += u[c][r];
        }

        xp += IN_DIM;
        wp += WROW;
    }

    // ---- store partials in C layout
    float* dst = part + (size_t)y * B_TOT * CD;
    #pragma unroll
    for (int c = 0; c < NC; c++)
        #pragma unroll
        for (int r = 0; r < 4; r++)
            dst[(size_t)(brow + r) * CD + c * OD + col] = acc[c][r];
}

// ===== Reduce, R9 rewrite: full-wave coalesced. Block = 256 thr (4 waves);
// thread (col=t&63, grp=t>>6) sums 32 slabs with 64-lane-contiguous 1KB
// reads (old layout did 128B segments + 8/64-lane epilogue, ~14us).
// 160 blocks; epilogue threads 0..63: scale/bias + round staging:
// store S_acc (round 0), add (round 1), squash -> v_out (round 2).
__global__ __launch_bounds__(256) void reduce_round(
    const float* __restrict__ part,   // [NS, B, 160]
    float* __restrict__ S_acc,        // [B, 160]
    float* __restrict__ v_out,        // [B, 10, 16]
    float scale, int round)
{
    __shared__ float4 sh[4][64];   // 4 KB

    const int col = threadIdx.x & 63;
    const int grp = threadIdx.x >> 6;               // 0..3
    const int g   = blockIdx.x * 64 + col;          // float4 column index

    const float4* p4 = (const float4*)part + (size_t)grp * NF4 + g;
    float4 s = { 0.f, 0.f, 0.f, 0.f };
    #pragma unroll 8
    for (int k = 0; k < NS / 4; k++) {              // slabs grp + 4k
        float4 t = p4[(size_t)k * 4 * NF4];
        s.x += t.x; s.y += t.y; s.z += t.z; s.w += t.w;
    }
    sh[grp][col] = s;
    __syncthreads();

    if (threadIdx.x < 64) {
        float4 t = { 0.f, 0.f, 0.f, 0.f };
        #pragma unroll
        for (int k = 0; k < 4; k++) {
            float4 q = sh[k][col];
            t.x += q.x; t.y += q.y; t.z += q.z; t.w += q.w;
        }
        t.x = t.x * scale + RBIAS;
        t.y = t.y * scale + RBIAS;
        t.z = t.z * scale + RBIAS;
        t.w = t.w * scale + RBIAS;

        if (round == 0) {
            ((float4*)S_acc)[g] = t;          // store — no memset required
        } else if (round == 1) {
            float4 o = ((float4*)S_acc)[g];
            o.x += t.x; o.y += t.y; o.z += t.z; o.w += t.w;
            ((float4*)S_acc)[g] = o;
        } else {
            // squash: 16 d = 4 consecutive float4 columns = lanes 4k..4k+3
            float ss = t.x * t.x + t.y * t.y + t.z * t.z + t.w * t.w;
            ss += __shfl_xor(ss, 1, 64);
            ss += __shfl_xor(ss, 2, 64);
            float norm = sqrtf(ss);
            float k2 = norm / (1.0f + ss);
            float4 v = { t.x * k2, t.y * k2, t.z * k2, t.w * k2 };
            ((float4*)v_out)[g] = v;
        }
    }
}

extern "C" void kernel_launch(void* const* d_in, const int* in_sizes, int n_in,
                              void* d_out, int out_size, void* d_ws, size_t ws_size,
                              hipStream_t stream) {
    const float* x = (const float*)d_in[0];   // [256,2304,8]
    const float* W = (const float*)d_in[1];   // [2304,8,160]
    float* out = (float*)d_out;               // [256,10,16]

    // Workspace (every byte written before read each call — re-poison safe)
    float* part  = (float*)d_ws;                            // NS * 40960  (~21 MB)
    float* S_acc = part + (size_t)NS * B_TOT * CD;          // 40960 floats

    const dim3 rgrid(256);           // 1 block/CU, 8 waves (512 thr)
    const int  RG = NF4 / 64;        // 160 reduce blocks

    // Round 0 (uniform cw; 0.1 folded into reduce scale; S_acc stored not added)
    routing_round<1><<<rgrid, 512, 0, stream>>>(x, W, S_acc, part);
    reduce_round<<<RG, 256, 0, stream>>>(part, S_acc, out, 0.1f, 0);

    // Round 1
    routing_round<0><<<rgrid, 512, 0, stream>>>(x, W, S_acc, part);
    reduce_round<<<RG, 256, 0, stream>>>(part, S_acc, out, 1.0f, 1);

    // Round 2 (+final squash fused)
    routing_round<0><<<rgrid, 512, 0, stream>>>(x, W, S_acc, part);
    reduce_round<<<RG, 256, 0, stream>>>(part, S_acc, out, 1.0f, 2);
}

// Round 10
// 202.054 us; speedup vs baseline: 1.9274x; 1.9274x over previous
//
#include <hip/hip_runtime.h>
#include <math.h>

// Problem constants (fixed by reference)
#define B_TOT   256
#define N_TOT   2304
#define IN_DIM  8
#define NC      10      // NUM_CLASSES
#define OD      16      // OUT_DIM
#define CD      160     // NC*OD
#define RBIAS   0.1f

// R3's proven geometry: 512 blocks = 2/CU, CU-paired on same n-range.
#define BTILE    64                      // b per block (= wave lanes)
#define NS       128                     // n-slices
#define NPB      (N_TOT / NS)            // 18 n per block
#define NTHREADS 640                     // 10 waves
#define XR       (NPB * IN_DIM + 4)      // 148: x row stride
#define LB       72                      // logit board row stride
#define WROW     (IN_DIM * CD)           // 1280 floats per W row
#define SRAW     (B_TOT * CD)            // 40960 floats per accumulator

#define NXCD     8

// ===== Routing round: R3 body VERBATIM (proven 49.4us; transport ledger
// R1-R9 closed: scalar-K$ W delivery is the best of 5 measured paths).
// R10 change is the EPILOGUE ONLY: instead of writing a [NS,B,160] part
// slab (20MB HBM write + 21MB reduce re-read + 16us reduce kernel, x3),
// blocks atomicAdd their register tile into rawT[cd][b] (160KB, L3-
// resident). Lane index = b -> 64 CONSECUTIVE dwords per wave-atomic
// (4-line RMWs, hardware-coalesced). fp32 atomic reorder ~1e-6 << tol.
template <int FIRST>
__global__ __launch_bounds__(NTHREADS) void routing_round(
    const float* __restrict__ x,      // [B, N, 8]
    const float* __restrict__ W,      // [N, 8, 160]
    const float* __restrict__ S_acc,  // [B, 160]
    float* __restrict__ rawT)         // [160][256] atomic accumulator
{
    __shared__ float sh_x[BTILE * XR];            // 37.9 KB
    __shared__ float sh_lg[2][NC * LB];           // 5.8 KB

    const int tid = threadIdx.x;

    // R3's CU-pair map: xcd = o&7 (XCD round-robin, confirmed R1 via FETCH
    // 55.5->21.4MB); breadth-first fill puts within-XCD ranks r and r+32 on
    // the same CU -> same (y, n-range), different b0: W lines shared by all
    // 20 waves of the CU.
    const int o      = blockIdx.x;                 // 0..511
    const int xcd    = o & (NXCD - 1);
    const int r      = o >> 3;                     // 0..63
    const int cuslot = r & 31;
    const int pairid = r >> 5;
    const int ySlab  = xcd * 16 + (cuslot & 15);   // 0..127
    const int b0     = ((cuslot >> 4) * 2 + pairid) * BTILE;
    const int n0     = ySlab * NPB;

    const int b   = tid & 63;
    const int cu  = __builtin_amdgcn_readfirstlane(tid >> 6);

    // ---- stage x tile: [64 b][144 floats], coalesced float4
    {
        const int XT4 = BTILE * (NPB * IN_DIM / 4);   // 2304
        for (int k = tid; k < XT4; k += NTHREADS) {
            int bb   = k / (NPB * 2);
            int off4 = k - bb * (NPB * 2);
            float4 v = *(const float4*)(x + ((size_t)(b0 + bb) * N_TOT + n0) * IN_DIM + off4 * 4);
            *(float4*)(&sh_x[bb * XR + off4 * 4]) = v;
        }
    }

    // ---- S fragment: all 16 d for (b, c)
    float S[OD];
    if (!FIRST) {
        const float4* sp = (const float4*)(S_acc + (size_t)(b0 + b) * CD + cu * OD);
        #pragma unroll
        for (int q = 0; q < 4; q++) ((float4*)S)[q] = sp[q];
    }

    float acc[OD];
    #pragma unroll
    for (int d = 0; d < OD; d++) acc[d] = 0.f;

    __syncthreads();   // sh_x ready

    const float* Wc = W + cu * OD;    // wave-uniform base -> scalar loads

    for (int nn = 0; nn < NPB; nn++) {
        float xf[IN_DIM];
        {
            const float4* xp = (const float4*)(&sh_x[b * XR + nn * IN_DIM]);
            ((float4*)xf)[0] = xp[0];
            ((float4*)xf)[1] = xp[1];
        }

        const float* Wn = Wc + (size_t)(n0 + nn) * WROW;
        float u[OD];
        #pragma unroll
        for (int d = 0; d < OD; d++) u[d] = xf[0] * Wn[d];
        #pragma unroll
        for (int i = 1; i < IN_DIM; i++) {
            const float* Wi = Wn + i * CD;
            #pragma unroll
            for (int d = 0; d < OD; d++) u[d] = fmaf(xf[i], Wi[d], u[d]);
        }

        if (!FIRST) {
            const int cur = nn & 1;
            float lg = 0.f;
            #pragma unroll
            for (int d = 0; d < OD; d++) lg = fmaf(u[d], S[d], lg);
            sh_lg[cur][cu * LB + b] = lg;
            __syncthreads();

            float m = -1e30f;
            float row[NC];
            #pragma unroll
            for (int k = 0; k < NC; k++) {
                row[k] = sh_lg[cur][k * LB + b];
                m = fmaxf(m, row[k]);
            }
            float den = 0.f;
            #pragma unroll
            for (int k = 0; k < NC; k++) den += __expf(row[k] - m);
            float cw = __expf(lg - m) / den;

            #pragma unroll
            for (int d = 0; d < OD; d++) acc[d] = fmaf(cw, u[d], acc[d]);
        } else {
            #pragma unroll
            for (int d = 0; d < OD; d++) acc[d] += u[d];
            // round 0: no barriers in the loop
        }
    }

    // ---- commit: 16 lane-coalesced atomic adds (64 consecutive dwords per
    // wave-instr). Replaces the 20MB part write + reduce kernel entirely.
    float* dst = rawT + b0 + b;
    #pragma unroll
    for (int d = 0; d < OD; d++)
        atomicAdd(dst + (size_t)(cu * OD + d) * B_TOT, acc[d]);
}

// ===== Zero the three raw accumulators (re-poison safe: first touch each
// call). 3*40960 floats = 30720 float4 -> 120 blocks x 256 threads exact.
__global__ __launch_bounds__(256) void zero_raws(float4* __restrict__ p)
{
    p[(size_t)blockIdx.x * 256 + threadIdx.x] = (float4){0.f, 0.f, 0.f, 0.f};
}

// ===== Finalize: 40 blocks x 256 threads, thread p owns float4 #p of the
// [B][160] view (p*4 = b*160 + c*16 + dq*4; b = p/40). Reads rawT[cd][b]
// (4 strided dwords, 160KB L3-hot), then:
//   mode 0: S_acc = raw*0.1 + 0.1          (round-0: uniform c folded)
//   mode 1: S_acc += raw + 0.1
//   mode 2: s = raw + 0.1; squash -> v_out (norm over 16 d via 2 shfl_xor:
//           the 4 dq-threads of one (b,c) are consecutive lanes, 4-aligned)
__global__ __launch_bounds__(256) void finalize_round(
    const float* __restrict__ rawT,   // [160][256]
    float* __restrict__ S_acc,        // [256][160]
    float* __restrict__ v_out,        // [256][10][16]
    int mode)
{
    const int p   = blockIdx.x * 256 + threadIdx.x;   // 0..10239
    const int b   = p / 40;
    const int rem = p - b * 40;                       // c*4 + dq
    const int cd0 = rem * 4;                          // = c*16 + dq*4

    float t0 = rawT[(size_t)(cd0 + 0) * B_TOT + b];
    float t1 = rawT[(size_t)(cd0 + 1) * B_TOT + b];
    float t2 = rawT[(size_t)(cd0 + 2) * B_TOT + b];
    float t3 = rawT[(size_t)(cd0 + 3) * B_TOT + b];

    if (mode == 0) {
        float4 o = { t0 * 0.1f + RBIAS, t1 * 0.1f + RBIAS,
                     t2 * 0.1f + RBIAS, t3 * 0.1f + RBIAS };
        ((float4*)S_acc)[p] = o;
    } else if (mode == 1) {
        float4 o = ((const float4*)S_acc)[p];
        o.x += t0 + RBIAS; o.y += t1 + RBIAS;
        o.z += t2 + RBIAS; o.w += t3 + RBIAS;
        ((float4*)S_acc)[p] = o;
    } else {
        const float s0 = t0 + RBIAS, s1 = t1 + RBIAS;
        const float s2 = t2 + RBIAS, s3 = t3 + RBIAS;
        float ss = s0 * s0 + s1 * s1 + s2 * s2 + s3 * s3;
        ss += __shfl_xor(ss, 1, 64);
        ss += __shfl_xor(ss, 2, 64);
        const float norm = sqrtf(ss);
        const float k2 = norm / (1.0f + ss);
        float4 v = { s0 * k2, s1 * k2, s2 * k2, s3 * k2 };
        ((float4*)v_out)[p] = v;
    }
}

extern "C" void kernel_launch(void* const* d_in, const int* in_sizes, int n_in,
                              void* d_out, int out_size, void* d_ws, size_t ws_size,
                              hipStream_t stream) {
    const float* x = (const float*)d_in[0];   // [256,2304,8]
    const float* W = (const float*)d_in[1];   // [2304,8,160]
    float* out = (float*)d_out;               // [256,10,16]

    // Workspace: 3 raw accumulators + S_acc = 655 KB total (was 21 MB part).
    // Every byte read is written first each call (zero_raws; S_acc via mode0).
    float* raw0  = (float*)d_ws;
    float* raw1  = raw0 + SRAW;
    float* raw2  = raw1 + SRAW;
    float* S_acc = raw2 + SRAW;

    const dim3 rgrid(512);    // 2/CU, CU-paired (R3)

    zero_raws<<<120, 256, 0, stream>>>((float4*)raw0);   // all 3 raws

    // Round 0 (uniform cw; 0.1 folded into finalize scale)
    routing_round<1><<<rgrid, NTHREADS, 0, stream>>>(x, W, S_acc, raw0);
    finalize_round<<<40, 256, 0, stream>>>(raw0, S_acc, out, 0);

    // Round 1
    routing_round<0><<<rgrid, NTHREADS, 0, stream>>>(x, W, S_acc, raw1);
    finalize_round<<<40, 256, 0, stream>>>(raw1, S_acc, out, 1);

    // Round 2 (+final squash)
    routing_round<0><<<rgrid, NTHREADS, 0, stream>>>(x, W, S_acc, raw2);
    finalize_round<<<40, 256, 0, stream>>>(raw2, S_acc, out, 2);
}